// Round 1
// baseline (93.844 us; speedup 1.0000x reference)
//
#include <hip/hip_runtime.h>
#include <math.h>

// BlockSharedRounding: forward = E2M1 hard quantization of |x|+delta with
// per-32-block delta = 0.5*tanh(delta_raw). Outputs: [abs_hard (f32), ord (as f32)].
//
// Memory-bound streaming kernel: 8 elems/thread (float4 x2 in, float4 x4 out).
// One 32-elem block spans 4 consecutive 8-elem groups -> exactly one tanh/thread.
// tanh computed in double then rounded to f32 to match correctly-rounded host
// tanh bit-exactly (bin boundaries are numerically razor-thin).

__global__ __launch_bounds__(256) void bsr_kernel(
    const float* __restrict__ x,
    const float* __restrict__ draw,
    float* __restrict__ out_val,
    float* __restrict__ out_ord,
    long long nGroups)
{
    const long long stride = (long long)gridDim.x * blockDim.x;
    for (long long g = (long long)blockIdx.x * blockDim.x + threadIdx.x;
         g < nGroups; g += stride) {
        // group g covers elements [8g, 8g+8); its 32-block index is g>>2
        float delta = 0.5f * (float)tanh((double)draw[g >> 2]);

        float4 x0 = reinterpret_cast<const float4*>(x)[2 * g];
        float4 x1 = reinterpret_cast<const float4*>(x)[2 * g + 1];
        float xs[8] = {x0.x, x0.y, x0.z, x0.w, x1.x, x1.y, x1.z, x1.w};
        float v[8], o[8];

        #pragma unroll
        for (int j = 0; j < 8; ++j) {
            float a = fabsf(xs[j]) + delta;   // exact f32 add, matches reference
            float val = 0.0f, ord = 0.0f;
            // ord = #bounds strictly below a (searchsorted left == sum(a > bounds))
            // val accumulates the VALUES[] step sizes: 0,0.5,1,1.5,2,3,4,6
            val += (a > 0.25f) ? 0.5f : 0.0f;  ord += (a > 0.25f) ? 1.0f : 0.0f;
            val += (a > 0.75f) ? 0.5f : 0.0f;  ord += (a > 0.75f) ? 1.0f : 0.0f;
            val += (a > 1.25f) ? 0.5f : 0.0f;  ord += (a > 1.25f) ? 1.0f : 0.0f;
            val += (a > 1.75f) ? 0.5f : 0.0f;  ord += (a > 1.75f) ? 1.0f : 0.0f;
            val += (a > 2.5f)  ? 1.0f : 0.0f;  ord += (a > 2.5f)  ? 1.0f : 0.0f;
            val += (a > 3.5f)  ? 1.0f : 0.0f;  ord += (a > 3.5f)  ? 1.0f : 0.0f;
            val += (a > 5.0f)  ? 2.0f : 0.0f;  ord += (a > 5.0f)  ? 1.0f : 0.0f;
            v[j] = val;
            o[j] = ord;
        }

        float4 v0 = {v[0], v[1], v[2], v[3]};
        float4 v1 = {v[4], v[5], v[6], v[7]};
        float4 o0 = {o[0], o[1], o[2], o[3]};
        float4 o1 = {o[4], o[5], o[6], o[7]};
        reinterpret_cast<float4*>(out_val)[2 * g]     = v0;
        reinterpret_cast<float4*>(out_val)[2 * g + 1] = v1;
        reinterpret_cast<float4*>(out_ord)[2 * g]     = o0;
        reinterpret_cast<float4*>(out_ord)[2 * g + 1] = o1;
    }
}

extern "C" void kernel_launch(void* const* d_in, const int* in_sizes, int n_in,
                              void* d_out, int out_size, void* d_ws, size_t ws_size,
                              hipStream_t stream) {
    const float* x    = (const float*)d_in[0];   // x_scaled, n elements
    const float* draw = (const float*)d_in[1];   // delta_raw, n/32 elements
    float* out = (float*)d_out;                  // [abs_hard | ord] concatenated

    long long n = (long long)in_sizes[0];        // 4096*8192, divisible by 8
    long long nGroups = n >> 3;                  // 8 elements per thread-group

    const int block = 256;
    long long wantBlocks = (nGroups + block - 1) / block;
    int grid = (int)(wantBlocks < 2048 ? wantBlocks : 2048);  // grid-stride cap

    bsr_kernel<<<grid, block, 0, stream>>>(x, draw, out, out + n, nGroups);
}

// Round 2
// 92.626 us; speedup vs baseline: 1.0131x; 1.0131x over previous
//
#include <hip/hip_runtime.h>
#include <math.h>

// BlockSharedRounding: forward = E2M1 hard quantization of |x|+delta,
// delta = 0.5*tanh(delta_raw) shared per 32-elem block.
// Outputs concatenated: [abs_hard (f32) | ord (int32 bit-pattern written as f32 values)].
//
// Two-kernel plan:
//   K1: delta[nb] = 0.5f * (float)tanh((double)draw[nb])  -> d_ws (4 MB)
//       (double tanh rounded to f32 == numpy's correctly-rounded f32 tanh; bin
//        boundaries are razor-thin so bit-exactness here is mandatory)
//   K2: pure streaming quantize, one float4 per thread per step, unit-stride.
// Fallback single kernel (tanh inline) if ws_size is too small.

__global__ __launch_bounds__(256) void bsr_delta_kernel(
    const float* __restrict__ draw, float* __restrict__ delta, int nb)
{
    int i = blockIdx.x * 256 + threadIdx.x;
    if (i < nb) delta[i] = 0.5f * (float)tanh((double)draw[i]);
}

__device__ __forceinline__ void quant4(float4 xv, float d, float4& val, float4& ordf)
{
    float xs[4] = {xv.x, xv.y, xv.z, xv.w};
    float vv[4], oo[4];
    #pragma unroll
    for (int j = 0; j < 4; ++j) {
        float a = fabsf(xs[j]) + d;          // abs folds into src modifier
        int o = 0;                           // ord = #bounds strictly below a
        o += a > 0.25f;
        o += a > 0.75f;
        o += a > 1.25f;
        o += a > 1.75f;
        o += a > 2.5f;
        o += a > 3.5f;
        o += a > 5.0f;
        // VALUES*2 packed as nibbles: {0,1,2,3,4,6,8,12} -> 0xC8643210
        vv[j] = (float)((0xC8643210u >> (o << 2)) & 0xFu) * 0.5f;
        oo[j] = (float)o;
    }
    val  = {vv[0], vv[1], vv[2], vv[3]};
    ordf = {oo[0], oo[1], oo[2], oo[3]};
}

__global__ __launch_bounds__(256) void bsr_main_kernel(
    const float4* __restrict__ x,
    const float* __restrict__ delta,   // per-32-block, precomputed
    float4* __restrict__ out_val,
    float4* __restrict__ out_ord,
    int nVec)                          // n/4, divisible by 2*T in practice
{
    const int T = gridDim.x * blockDim.x;
    int v = blockIdx.x * blockDim.x + threadIdx.x;
    for (; v + T < nVec; v += 2 * T) {
        // two independent unit-stride streams for MLP
        float d0 = delta[v >> 3];
        float d1 = delta[(v + T) >> 3];
        float4 x0 = x[v];
        float4 x1 = x[v + T];
        float4 v0, o0, v1, o1;
        quant4(x0, d0, v0, o0);
        quant4(x1, d1, v1, o1);
        out_val[v]     = v0;
        out_ord[v]     = o0;
        out_val[v + T] = v1;
        out_ord[v + T] = o1;
    }
    if (v < nVec) {
        float d = delta[v >> 3];
        float4 xv = x[v];
        float4 vv, ov;
        quant4(xv, d, vv, ov);
        out_val[v] = vv;
        out_ord[v] = ov;
    }
}

// Fallback: monolithic kernel with inline DP tanh (used only if ws too small).
__global__ __launch_bounds__(256) void bsr_fallback_kernel(
    const float* __restrict__ x,
    const float* __restrict__ draw,
    float* __restrict__ out_val,
    float* __restrict__ out_ord,
    long long nGroups)
{
    const long long stride = (long long)gridDim.x * blockDim.x;
    for (long long g = (long long)blockIdx.x * blockDim.x + threadIdx.x;
         g < nGroups; g += stride) {
        float delta = 0.5f * (float)tanh((double)draw[g >> 2]);
        float4 x0 = reinterpret_cast<const float4*>(x)[2 * g];
        float4 x1 = reinterpret_cast<const float4*>(x)[2 * g + 1];
        float4 v0, o0, v1, o1;
        quant4(x0, delta, v0, o0);
        quant4(x1, delta, v1, o1);
        reinterpret_cast<float4*>(out_val)[2 * g]     = v0;
        reinterpret_cast<float4*>(out_val)[2 * g + 1] = v1;
        reinterpret_cast<float4*>(out_ord)[2 * g]     = o0;
        reinterpret_cast<float4*>(out_ord)[2 * g + 1] = o1;
    }
}

extern "C" void kernel_launch(void* const* d_in, const int* in_sizes, int n_in,
                              void* d_out, int out_size, void* d_ws, size_t ws_size,
                              hipStream_t stream) {
    const float* x    = (const float*)d_in[0];   // x_scaled, n elements
    const float* draw = (const float*)d_in[1];   // delta_raw, n/32 elements
    float* out = (float*)d_out;

    long long n  = (long long)in_sizes[0];       // 33,554,432
    int nb       = in_sizes[1];                  // n/32 = 1,048,576
    int nVec     = (int)(n >> 2);                // n/4

    if (ws_size >= (size_t)nb * sizeof(float)) {
        float* delta = (float*)d_ws;
        bsr_delta_kernel<<<(nb + 255) / 256, 256, 0, stream>>>(draw, delta, nb);
        const int block = 256;
        int grid = 2048;                         // 32 waves/CU, grid-stride
        bsr_main_kernel<<<grid, block, 0, stream>>>(
            reinterpret_cast<const float4*>(x), delta,
            reinterpret_cast<float4*>(out),
            reinterpret_cast<float4*>(out + n), nVec);
    } else {
        long long nGroups = n >> 3;
        const int block = 256;
        long long wantBlocks = (nGroups + block - 1) / block;
        int grid = (int)(wantBlocks < 2048 ? wantBlocks : 2048);
        bsr_fallback_kernel<<<grid, block, 0, stream>>>(x, draw, out, out + n, nGroups);
    }
}

// Round 3
// 74.928 us; speedup vs baseline: 1.2525x; 1.2362x over previous
//
#include <hip/hip_runtime.h>
#include <math.h>

// BlockSharedRounding: forward = E2M1 hard quantization of |x|+delta,
// delta = 0.5*tanh(delta_raw) shared per 32-elem block.
// Outputs concatenated: [abs_hard (f32) | ord (f32)].
//
//   K1: delta[nb] = 0.5f * (float)tanh((double)draw[nb])  -> d_ws
//       (double tanh rounded to f32 == correctly-rounded f32 tanh; bin
//        boundaries are razor-thin so bit-exactness is mandatory)
//   K2: streaming quantize, unit-stride float4, NONTEMPORAL stores.
//       Outputs are write-once/never-read -> nt stores keep them from
//       allocating in L2/L3, so x (134 MB) can stay L3-resident across
//       graph replays and writes stream at near fill-kernel rate.

typedef float f32x4 __attribute__((ext_vector_type(4)));

__global__ __launch_bounds__(256) void bsr_delta_kernel(
    const float* __restrict__ draw, float* __restrict__ delta, int nb)
{
    int i = blockIdx.x * 256 + threadIdx.x;
    if (i < nb) delta[i] = 0.5f * (float)tanh((double)draw[i]);
}

__device__ __forceinline__ void quant4(f32x4 xv, float d, f32x4& val, f32x4& ordf)
{
    #pragma unroll
    for (int j = 0; j < 4; ++j) {
        float a = fabsf(xv[j]) + d;          // abs folds into src modifier
        int o = 0;                           // ord = #bounds strictly below a
        o += a > 0.25f;
        o += a > 0.75f;
        o += a > 1.25f;
        o += a > 1.75f;
        o += a > 2.5f;
        o += a > 3.5f;
        o += a > 5.0f;
        // VALUES*2 packed as nibbles: {0,1,2,3,4,6,8,12} -> 0xC8643210
        val[j]  = (float)((0xC8643210u >> (o << 2)) & 0xFu) * 0.5f;
        ordf[j] = (float)o;
    }
}

__global__ __launch_bounds__(256) void bsr_main_kernel(
    const f32x4* __restrict__ x,
    const float* __restrict__ delta,   // per-32-block, precomputed
    f32x4* __restrict__ out_val,
    f32x4* __restrict__ out_ord,
    int nVec)                          // n/4
{
    const int T = gridDim.x * blockDim.x;
    int v = blockIdx.x * blockDim.x + threadIdx.x;
    for (; v + T < nVec; v += 2 * T) {
        // two independent unit-stride streams for MLP
        float d0 = delta[v >> 3];
        float d1 = delta[(v + T) >> 3];
        f32x4 x0 = x[v];
        f32x4 x1 = x[v + T];
        f32x4 v0, o0, v1, o1;
        quant4(x0, d0, v0, o0);
        quant4(x1, d1, v1, o1);
        __builtin_nontemporal_store(v0, &out_val[v]);
        __builtin_nontemporal_store(o0, &out_ord[v]);
        __builtin_nontemporal_store(v1, &out_val[v + T]);
        __builtin_nontemporal_store(o1, &out_ord[v + T]);
    }
    if (v < nVec) {
        float d = delta[v >> 3];
        f32x4 xv = x[v];
        f32x4 vv, ov;
        quant4(xv, d, vv, ov);
        __builtin_nontemporal_store(vv, &out_val[v]);
        __builtin_nontemporal_store(ov, &out_ord[v]);
    }
}

// Fallback: monolithic kernel with inline DP tanh (used only if ws too small).
__global__ __launch_bounds__(256) void bsr_fallback_kernel(
    const float* __restrict__ x,
    const float* __restrict__ draw,
    float* __restrict__ out_val,
    float* __restrict__ out_ord,
    long long nGroups)
{
    const long long stride = (long long)gridDim.x * blockDim.x;
    for (long long g = (long long)blockIdx.x * blockDim.x + threadIdx.x;
         g < nGroups; g += stride) {
        float delta = 0.5f * (float)tanh((double)draw[g >> 2]);
        f32x4 x0 = reinterpret_cast<const f32x4*>(x)[2 * g];
        f32x4 x1 = reinterpret_cast<const f32x4*>(x)[2 * g + 1];
        f32x4 v0, o0, v1, o1;
        quant4(x0, delta, v0, o0);
        quant4(x1, delta, v1, o1);
        __builtin_nontemporal_store(v0, &reinterpret_cast<f32x4*>(out_val)[2 * g]);
        __builtin_nontemporal_store(v1, &reinterpret_cast<f32x4*>(out_val)[2 * g + 1]);
        __builtin_nontemporal_store(o0, &reinterpret_cast<f32x4*>(out_ord)[2 * g]);
        __builtin_nontemporal_store(o1, &reinterpret_cast<f32x4*>(out_ord)[2 * g + 1]);
    }
}

extern "C" void kernel_launch(void* const* d_in, const int* in_sizes, int n_in,
                              void* d_out, int out_size, void* d_ws, size_t ws_size,
                              hipStream_t stream) {
    const float* x    = (const float*)d_in[0];   // x_scaled, n elements
    const float* draw = (const float*)d_in[1];   // delta_raw, n/32 elements
    float* out = (float*)d_out;

    long long n  = (long long)in_sizes[0];       // 33,554,432
    int nb       = in_sizes[1];                  // n/32 = 1,048,576
    int nVec     = (int)(n >> 2);                // n/4

    if (ws_size >= (size_t)nb * sizeof(float)) {
        float* delta = (float*)d_ws;
        bsr_delta_kernel<<<(nb + 255) / 256, 256, 0, stream>>>(draw, delta, nb);
        const int block = 256;
        int grid = 2048;                         // grid-stride, 32 waves/CU
        bsr_main_kernel<<<grid, block, 0, stream>>>(
            reinterpret_cast<const f32x4*>(x), delta,
            reinterpret_cast<f32x4*>(out),
            reinterpret_cast<f32x4*>(out + n), nVec);
    } else {
        long long nGroups = n >> 3;
        const int block = 256;
        long long wantBlocks = (nGroups + block - 1) / block;
        int grid = (int)(wantBlocks < 2048 ? wantBlocks : 2048);
        bsr_fallback_kernel<<<grid, block, 0, stream>>>(x, draw, out, out + n, nGroups);
    }
}